// Round 1
// 448.756 us; speedup vs baseline: 1.0187x; 1.0187x over previous
//
#include <hip/hip_runtime.h>

typedef unsigned short u16;
typedef unsigned int u32;
typedef __attribute__((ext_vector_type(8))) short short8;
typedef __attribute__((ext_vector_type(4))) float f32x4;

__device__ __forceinline__ u16 f2bf(float f) {
    u32 u = __float_as_uint(f);
    return (u16)((u + 0x7FFFu + ((u >> 16) & 1u)) >> 16);
}

// async global->LDS, 16B per lane. LDS dest is wave-uniform base (+lane*16 implicit).
// Casts go through u64: flat->AS1 numeric identity; flat LDS low 32 bits == AS3 offset.
__device__ __forceinline__ void gld16(const u16* g, u16* l) {
    __builtin_amdgcn_global_load_lds(
        (const __attribute__((address_space(1))) unsigned int*)(unsigned long long)(const void*)g,
        (__attribute__((address_space(3))) unsigned int*)(unsigned long long)(void*)l,
        16, 0, 0);
}

// ---------------------------------------------------------------------------
// Kernel 0a: NCHW fp32 -> halo-padded NHWC bf16
// xp layout: [32][66][66][256]; interior at [ho+1][wo+1]; halo ring zeroed here
// (re-zeroed every launch so workspace re-poisoning between iters is safe).
// Block = (n, icb of 64 ch, image row). float4 reads, dwordx4 bf16 writes.
// ---------------------------------------------------------------------------
__global__ __launch_bounds__(256) void nchw2nhwc_pad(const float* __restrict__ x,
                                                     u16* __restrict__ xp) {
    __shared__ float tile[64][66];   // [ch][px], stride 66 -> 2-way (free) on write
    const int tid = threadIdx.x;
    const int b   = blockIdx.x;
    const int n   = b >> 8;          // 32 images
    const int icb = (b >> 6) & 3;    // 4 blocks of 64 ch
    const int row = b & 63;          // image row
    const int ic0 = icb * 64;

    // read: 64 ch x 64 px, float4 per lane; 4 segments x 256B per wave instr
    const int q = tid & 15, r0 = tid >> 4;
    const float* src = x + (size_t)(n * 256 + ic0) * 4096 + row * 64 + q * 4;
#pragma unroll
    for (int rr = 0; rr < 4; ++rr) {
        const int r = r0 + rr * 16;
        const float4 v = *(const float4*)(src + (size_t)r * 4096);
        float2* t0 = (float2*)&tile[r][q * 4];   // 264B row stride: 8B aligned
        t0[0] = make_float2(v.x, v.y);
        t0[1] = make_float2(v.z, v.w);
    }
    __syncthreads();

    // write: per pass 32 px x 8 ch-chunks; 8 lanes x 16B = 128B contiguous per px
    const int c = tid & 7, ph = tid >> 3;
    u16* dst = xp + ((size_t)n * 4356 + (size_t)(row + 1) * 66 + 1) * 256 + ic0 + c * 8;
#pragma unroll
    for (int pp = 0; pp < 2; ++pp) {
        const int p = ph + pp * 32;
        u32 w0[4];
#pragma unroll
        for (int k = 0; k < 4; ++k) {
            const float f0 = tile[c * 8 + 2 * k][p];
            const float f1 = tile[c * 8 + 2 * k + 1][p];
            w0[k] = ((u32)f2bf(f1) << 16) | f2bf(f0);
        }
        uint4 v4; v4.x = w0[0]; v4.y = w0[1]; v4.z = w0[2]; v4.w = w0[3];
        *(uint4*)(dst + (size_t)p * 256) = v4;
    }

    // halo zeroing (each region owned by exactly one block)
    u16* hrow = xp + ((size_t)n * 4356 + (size_t)(row + 1) * 66) * 256 + ic0;
    if (tid < 64) {                                   // wp = 0 and wp = 65 of this row
        const int wp = (tid >> 5) ? 65 : 0;
        *(u32*)(hrow + (size_t)wp * 256 + (tid & 31) * 2) = 0u;
    }
    if (row == 0) {                                   // top row hp = 0 (66 px x 64 ch)
        u16* tb = xp + (size_t)n * 4356 * 256 + ic0;
        for (int i = tid; i < 2112; i += 256)
            *(u32*)(tb + (size_t)(i >> 5) * 256 + (i & 31) * 2) = 0u;
    }
    if (row == 63) {                                  // bottom row hp = 65
        u16* bb = xp + ((size_t)n * 4356 + 65 * 66) * 256 + ic0;
        for (int i = tid; i < 2112; i += 256)
            *(u32*)(bb + (size_t)(i >> 5) * 256 + (i & 31) * 2) = 0u;
    }
}

// ---------------------------------------------------------------------------
// Kernel 0b: hypernet weight generation -> bf16 weights, TAP-MAJOR layout:
// wb[oc][k] with k = tap*256 + ic   (ic contiguous per tap => contiguous K
// chunks matching the padded-NHWC channel dim)
// ---------------------------------------------------------------------------
__global__ __launch_bounds__(256) void wgen(const float* __restrict__ z,
                                            const float* __restrict__ W1,
                                            const float* __restrict__ B1,
                                            const float* __restrict__ W2,
                                            const float* __restrict__ B2,
                                            u16* __restrict__ wb) {
    __shared__ float zl[64];
    __shared__ float aL[1024];
    const int l = blockIdx.x;
    const int tid = threadIdx.x;
    if (tid < 64) zl[tid] = z[l * 64 + tid];
    __syncthreads();
#pragma unroll
    for (int i = 0; i < 4; ++i) {
        int idx = i * 256 + tid;            // = b*64 + d
        const float* wrow = W1 + (size_t)idx * 64;
        float s = B1[idx];
        for (int nn = 0; nn < 64; ++nn) s += wrow[nn] * zl[nn];
        aL[idx] = s;
    }
    __syncthreads();
    const int b1 = tid >> 4, b2 = tid & 15;
    const int ob = l >> 4, ib = l & 15;
    const int ic = ib * 16 + b1;
    const int oc = ob * 16 + b2;
    const size_t wbase = (size_t)oc * 2304 + ic;
    const float* arow = aL + b1 * 64;
#pragma unroll
    for (int tap = 0; tap < 9; ++tap) {
        int kk = b2 * 9 + tap;
        const float* w2row = W2 + (size_t)(b1 * 144 + kk) * 64;
        float s = B2[b1 * 144 + kk];
        for (int d = 0; d < 64; ++d) s += w2row[d] * arow[d];
        wb[wbase + (size_t)tap * 256] = f2bf(s);
    }
}

// ---------------------------------------------------------------------------
// Kernel 1: implicit-GEMM conv. M=oc(256) N=pixels(131072) K=2304 (tap-major).
// 128x128 tile, BK=32, 4 waves, 4x4 MFMA 16x16x32 bf16 per wave.
// global_load_lds(16B) staging, double-buffered LDS, ONE barrier per K-step
// (syncthreads' vmcnt(0) drain is the pipeline sync; next-step stage issued
// right after the barrier, overlapping this step's ds_read+MFMA).
// XOR slot-swizzle (phys slot s holds logical s^(row&3)) via pre-swizzled
// global source; read side uses slot lq^(lr&3) -> 4-way instead of 8-way.
// Halo padding removes all boundary masks.
// ---------------------------------------------------------------------------
__global__ __launch_bounds__(256) void conv_mfma(const u16* __restrict__ xp,
                                                 const u16* __restrict__ wb,
                                                 float* __restrict__ out) {
    __shared__ __align__(16) u16 As[2][128 * 32];   // [oc_r][k]  2 x 8 KB
    __shared__ __align__(16) u16 Bs[2][128 * 32];   // [px][ic]   2 x 8 KB

    const int tid = threadIdx.x;
    // XCD-chunked bijective swizzle: nwg=2048, 8 XCDs, 256 logical tiles/XCD
    const int b0  = blockIdx.x;
    const int bid = (b0 & 7) * 256 + (b0 >> 3);
    const int mt = bid & 1;              // oc tile
    const int nt = bid >> 1;             // pixel tile: 0..1023
    const int n = nt >> 5;               // image
    const int pimg = (nt & 31) << 7;     // 2 image rows per tile
    const int oc0 = mt << 7;

    const int lane = tid & 63;
    const int wave = tid >> 6;
    const int wm = (wave >> 1) & 1, wn = wave & 1;
    const int lr = lane & 15, lq = lane >> 4;
    const int sw = (lq ^ (lr & 3)) * 8;            // swizzled frag-read slot

    // staging geometry: wave stages 2 chunks of 16 rows for A and B each
    const int ls = lane >> 2;                      // row within chunk
    const int swst = ((lane & 3) ^ (ls & 3)) * 8;  // pre-swizzled source slot
    const int rr0 = wave * 32 + ls;
    const int rr1 = rr0 + 16;
    const u16* wbA0 = wb + (size_t)(oc0 + rr0) * 2304 + swst;
    const u16* wbA1 = wb + (size_t)(oc0 + rr1) * 2304 + swst;
    const int p0 = pimg + rr0, p1 = pimg + rr1;
    const int pb0 = ((p0 >> 6) + 1) * 66 + (p0 & 63) + 1;   // padded pixel idx
    const int pb1 = ((p1 >> 6) + 1) * 66 + (p1 & 63) + 1;
    const u16* xpN = xp + (size_t)n * 4356 * 256 + swst;

    auto stage = [&](int bi, int kt) {
        const int tap = kt >> 3, icb = kt & 7;
        const int t3 = tap / 3;
        const int dh = t3 - 1, dw = tap - t3 * 3 - 1;
        const int ko = tap * 256 + icb * 32;
        const int bo = (dh * 66 + dw) * 256 + icb * 32;   // pb*256+bo >= 0 always
        u16* ab = &As[bi][wave * 1024];
        u16* bb = &Bs[bi][wave * 1024];
        gld16(wbA0 + ko, ab);
        gld16(wbA1 + ko, ab + 512);
        gld16(xpN + (pb0 * 256 + bo), bb);
        gld16(xpN + (pb1 * 256 + bo), bb + 512);
    };

    f32x4 acc[4][4];
    const f32x4 z4 = {0.f, 0.f, 0.f, 0.f};
#pragma unroll
    for (int i = 0; i < 4; ++i)
#pragma unroll
        for (int j = 0; j < 4; ++j) acc[i][j] = z4;

    stage(0, 0);
#pragma unroll 2
    for (int kt = 0; kt < 72; ++kt) {
        const int cur = kt & 1;
        __syncthreads();                 // drains vmcnt(0): buf[cur] staged; prev reads done
        if (kt < 71) stage(cur ^ 1, kt + 1);   // in flight across ds_read+MFMA below

        const u16* Ab = &As[cur][0];
        const u16* Bb = &Bs[cur][0];
        short8 af[4], bf[4];
#pragma unroll
        for (int i = 0; i < 4; ++i) {
            af[i] = *(const short8*)(Ab + (wm * 64 + i * 16 + lr) * 32 + sw);
            bf[i] = *(const short8*)(Bb + (wn * 64 + i * 16 + lr) * 32 + sw);
        }
#pragma unroll
        for (int i = 0; i < 4; ++i)
#pragma unroll
            for (int j = 0; j < 4; ++j)
                acc[i][j] = __builtin_amdgcn_mfma_f32_16x16x32_bf16(
                    af[i], bf[j], acc[i][j], 0, 0, 0);
    }

    // epilogue: C/D layout col=lane&15 (pixel), row=lq*4+reg (oc)
    const size_t outn = (size_t)n * 256 * 4096;
#pragma unroll
    for (int i = 0; i < 4; ++i) {
        const int ocb = oc0 + wm * 64 + i * 16 + lq * 4;
#pragma unroll
        for (int j = 0; j < 4; ++j) {
            const int po = pimg + wn * 64 + j * 16 + lr;
            float* op = out + outn + (size_t)ocb * 4096 + po;
#pragma unroll
            for (int r = 0; r < 4; ++r) op[(size_t)r * 4096] = acc[i][j][r];
        }
    }
}

extern "C" void kernel_launch(void* const* d_in, const int* in_sizes, int n_in,
                              void* d_out, int out_size, void* d_ws, size_t ws_size,
                              hipStream_t stream) {
    const float* x  = (const float*)d_in[0];   // 32*256*64*64
    const float* z  = (const float*)d_in[1];   // 256*64
    const float* W1 = (const float*)d_in[2];   // 16*64*64
    const float* B1 = (const float*)d_in[3];   // 16*64
    const float* W2 = (const float*)d_in[4];   // 16*144*64
    const float* B2 = (const float*)d_in[5];   // 16*144
    float* out = (float*)d_out;

    u16* xp = (u16*)d_ws;                          // 32*66*66*256 bf16 = 68.1 MiB
    u16* wb = xp + (size_t)32 * 4356 * 256;        // 256*2304 bf16 = 1.125 MiB
    const size_t need = ((size_t)32 * 4356 * 256 + (size_t)256 * 2304) * 2;
    if (ws_size < need) return;  // ws too small for padded NHWC staging path

    nchw2nhwc_pad<<<dim3(8192), dim3(256), 0, stream>>>(x, xp);
    wgen<<<dim3(256), dim3(256), 0, stream>>>(z, W1, B1, W2, B2, wb);
    conv_mfma<<<dim3(2048), dim3(256), 0, stream>>>(xp, wb, out);
}

// Round 2
// 426.752 us; speedup vs baseline: 1.0712x; 1.0516x over previous
//
#include <hip/hip_runtime.h>

typedef unsigned short u16;
typedef unsigned int u32;
typedef __attribute__((ext_vector_type(8))) short short8;
typedef __attribute__((ext_vector_type(4))) float f32x4;

__device__ __forceinline__ u16 f2bf(float f) {
    u32 u = __float_as_uint(f);
    return (u16)((u + 0x7FFFu + ((u >> 16) & 1u)) >> 16);
}

// async global->LDS, 16B per lane. LDS dest is wave-uniform base (+lane*16 implicit).
__device__ __forceinline__ void gld16(const u16* g, u16* l) {
    __builtin_amdgcn_global_load_lds(
        (const __attribute__((address_space(1))) unsigned int*)(unsigned long long)(const void*)g,
        (__attribute__((address_space(3))) unsigned int*)(unsigned long long)(void*)l,
        16, 0, 0);
}

// ---------------------------------------------------------------------------
// Kernel 0a: NCHW fp32 -> halo-padded NHWC bf16  (unchanged from prev round)
// xp layout: [32][66][66][256]; interior at [ho+1][wo+1]; halo ring zeroed here.
// ---------------------------------------------------------------------------
__global__ __launch_bounds__(256) void nchw2nhwc_pad(const float* __restrict__ x,
                                                     u16* __restrict__ xp) {
    __shared__ float tile[64][66];
    const int tid = threadIdx.x;
    const int b   = blockIdx.x;
    const int n   = b >> 8;
    const int icb = (b >> 6) & 3;
    const int row = b & 63;
    const int ic0 = icb * 64;

    const int q = tid & 15, r0 = tid >> 4;
    const float* src = x + (size_t)(n * 256 + ic0) * 4096 + row * 64 + q * 4;
#pragma unroll
    for (int rr = 0; rr < 4; ++rr) {
        const int r = r0 + rr * 16;
        const float4 v = *(const float4*)(src + (size_t)r * 4096);
        float2* t0 = (float2*)&tile[r][q * 4];
        t0[0] = make_float2(v.x, v.y);
        t0[1] = make_float2(v.z, v.w);
    }
    __syncthreads();

    const int c = tid & 7, ph = tid >> 3;
    u16* dst = xp + ((size_t)n * 4356 + (size_t)(row + 1) * 66 + 1) * 256 + ic0 + c * 8;
#pragma unroll
    for (int pp = 0; pp < 2; ++pp) {
        const int p = ph + pp * 32;
        u32 w0[4];
#pragma unroll
        for (int k = 0; k < 4; ++k) {
            const float f0 = tile[c * 8 + 2 * k][p];
            const float f1 = tile[c * 8 + 2 * k + 1][p];
            w0[k] = ((u32)f2bf(f1) << 16) | f2bf(f0);
        }
        uint4 v4; v4.x = w0[0]; v4.y = w0[1]; v4.z = w0[2]; v4.w = w0[3];
        *(uint4*)(dst + (size_t)p * 256) = v4;
    }

    u16* hrow = xp + ((size_t)n * 4356 + (size_t)(row + 1) * 66) * 256 + ic0;
    if (tid < 64) {
        const int wp = (tid >> 5) ? 65 : 0;
        *(u32*)(hrow + (size_t)wp * 256 + (tid & 31) * 2) = 0u;
    }
    if (row == 0) {
        u16* tb = xp + (size_t)n * 4356 * 256 + ic0;
        for (int i = tid; i < 2112; i += 256)
            *(u32*)(tb + (size_t)(i >> 5) * 256 + (i & 31) * 2) = 0u;
    }
    if (row == 63) {
        u16* bb = xp + ((size_t)n * 4356 + 65 * 66) * 256 + ic0;
        for (int i = tid; i < 2112; i += 256)
            *(u32*)(bb + (size_t)(i >> 5) * 256 + (i & 31) * 2) = 0u;
    }
}

// ---------------------------------------------------------------------------
// Kernel 0b REWRITE: hypernet weight generation, LDS-resident.
// Grid 64 = 16 b1-blocks x 4 l-chunks(64). Per block: stage z-chunk, W1[b],
// W2[b] once (float4 coalesced), then:
//   pass1: a[l][d]  = B1[b][d]  + sum_n W1[b][d][n]*z[l][n]     (thread = l x d-group)
//   pass2: K[l][kk] = B2[b][kk] + sum_d W2[b][kk][d]*a[l][d]    (thread = l x kk-group)
// Per-lane LDS rows padded to 65 floats -> conflict-free; W1/W2 reads are
// wave-uniform float4 broadcasts. Output: same tap-major wb layout as before:
// wb[(ob*16+b2)*2304 + tap*256 + ib*16 + b1].
// ---------------------------------------------------------------------------
__global__ __launch_bounds__(256) void wgen(const float* __restrict__ z,
                                            const float* __restrict__ W1,
                                            const float* __restrict__ B1,
                                            const float* __restrict__ W2,
                                            const float* __restrict__ B2,
                                            u16* __restrict__ wb) {
    __shared__ float zl[64][65];     // [l][n]
    __shared__ float w1s[4096];      // [d][n] flat
    __shared__ float aS[64][65];     // [l][d]
    __shared__ float w2s[9216];      // [kk][d] flat

    const int tid = threadIdx.x;
    const int b   = blockIdx.x >> 2;    // b1 block 0..15
    const int lc  = blockIdx.x & 3;     // l-chunk 0..3
    const int l   = tid & 63;           // lane = local latent index
    const int g   = tid >> 6;           // wave 0..3

    // --- stage z chunk (64x64), W1[b] (64x64), W2[b] (144x64), all float4 ---
    const float* zg  = z  + (size_t)lc * 4096;
    const float* w1g = W1 + (size_t)b * 4096;
    const float* w2g = W2 + (size_t)b * 9216;
#pragma unroll
    for (int k = 0; k < 4; ++k) {
        const int i4 = tid + k * 256;
        const float4 v = *(const float4*)(zg + (size_t)i4 * 4);
        const int lr = i4 >> 4, nr = (i4 * 4) & 63;
        zl[lr][nr] = v.x; zl[lr][nr + 1] = v.y; zl[lr][nr + 2] = v.z; zl[lr][nr + 3] = v.w;
        *(float4*)(w1s + (size_t)i4 * 4) = *(const float4*)(w1g + (size_t)i4 * 4);
    }
#pragma unroll
    for (int k = 0; k < 9; ++k) {
        const int i4 = tid + k * 256;
        *(float4*)(w2s + (size_t)i4 * 4) = *(const float4*)(w2g + (size_t)i4 * 4);
    }
    __syncthreads();

    // --- pass 1: a[l][d] for d in [g*16, g*16+16) ---
    {
        float acc[16];
#pragma unroll
        for (int j = 0; j < 16; ++j) acc[j] = B1[b * 64 + g * 16 + j];
#pragma unroll
        for (int nb = 0; nb < 16; ++nb) {
            float zv0 = zl[l][nb * 4 + 0];
            float zv1 = zl[l][nb * 4 + 1];
            float zv2 = zl[l][nb * 4 + 2];
            float zv3 = zl[l][nb * 4 + 3];
#pragma unroll
            for (int j = 0; j < 16; ++j) {
                const float4 w = *(const float4*)(w1s + (g * 16 + j) * 64 + nb * 4);
                acc[j] += w.x * zv0 + w.y * zv1 + w.z * zv2 + w.w * zv3;
            }
        }
#pragma unroll
        for (int j = 0; j < 16; ++j) aS[l][g * 16 + j] = acc[j];
    }
    __syncthreads();

    // --- pass 2: K[l][kk] for kk in [g*36, g*36+36) ---
    float acc2[36];
#pragma unroll
    for (int t = 0; t < 36; ++t) acc2[t] = B2[b * 144 + g * 36 + t];
#pragma unroll
    for (int db = 0; db < 16; ++db) {
        float av0 = aS[l][db * 4 + 0];
        float av1 = aS[l][db * 4 + 1];
        float av2 = aS[l][db * 4 + 2];
        float av3 = aS[l][db * 4 + 3];
#pragma unroll
        for (int t = 0; t < 36; ++t) {
            const float4 w = *(const float4*)(w2s + (g * 36 + t) * 64 + db * 4);
            acc2[t] += w.x * av0 + w.y * av1 + w.z * av2 + w.w * av3;
        }
    }

    // --- scatter to wb: kk = g*36+t -> b2 = 4g + t/9, tap = t%9 (exact) ---
    const int lg = lc * 64 + l;
    const int ob = lg >> 4, ib = lg & 15;
#pragma unroll
    for (int t = 0; t < 36; ++t) {
        const int b2 = 4 * g + t / 9;
        const int tap = t % 9;
        wb[(size_t)(ob * 16 + b2) * 2304 + tap * 256 + ib * 16 + b] = f2bf(acc2[t]);
    }
}

// ---------------------------------------------------------------------------
// Kernel 1: implicit-GEMM conv (unchanged from prev round).
// ---------------------------------------------------------------------------
__global__ __launch_bounds__(256) void conv_mfma(const u16* __restrict__ xp,
                                                 const u16* __restrict__ wb,
                                                 float* __restrict__ out) {
    __shared__ __align__(16) u16 As[2][128 * 32];
    __shared__ __align__(16) u16 Bs[2][128 * 32];

    const int tid = threadIdx.x;
    const int b0  = blockIdx.x;
    const int bid = (b0 & 7) * 256 + (b0 >> 3);
    const int mt = bid & 1;
    const int nt = bid >> 1;
    const int n = nt >> 5;
    const int pimg = (nt & 31) << 7;
    const int oc0 = mt << 7;

    const int lane = tid & 63;
    const int wave = tid >> 6;
    const int wm = (wave >> 1) & 1, wn = wave & 1;
    const int lr = lane & 15, lq = lane >> 4;
    const int sw = (lq ^ (lr & 3)) * 8;

    const int ls = lane >> 2;
    const int swst = ((lane & 3) ^ (ls & 3)) * 8;
    const int rr0 = wave * 32 + ls;
    const int rr1 = rr0 + 16;
    const u16* wbA0 = wb + (size_t)(oc0 + rr0) * 2304 + swst;
    const u16* wbA1 = wb + (size_t)(oc0 + rr1) * 2304 + swst;
    const int p0 = pimg + rr0, p1 = pimg + rr1;
    const int pb0 = ((p0 >> 6) + 1) * 66 + (p0 & 63) + 1;
    const int pb1 = ((p1 >> 6) + 1) * 66 + (p1 & 63) + 1;
    const u16* xpN = xp + (size_t)n * 4356 * 256 + swst;

    auto stage = [&](int bi, int kt) {
        const int tap = kt >> 3, icb = kt & 7;
        const int t3 = tap / 3;
        const int dh = t3 - 1, dw = tap - t3 * 3 - 1;
        const int ko = tap * 256 + icb * 32;
        const int bo = (dh * 66 + dw) * 256 + icb * 32;
        u16* ab = &As[bi][wave * 1024];
        u16* bb = &Bs[bi][wave * 1024];
        gld16(wbA0 + ko, ab);
        gld16(wbA1 + ko, ab + 512);
        gld16(xpN + (pb0 * 256 + bo), bb);
        gld16(xpN + (pb1 * 256 + bo), bb + 512);
    };

    f32x4 acc[4][4];
    const f32x4 z4 = {0.f, 0.f, 0.f, 0.f};
#pragma unroll
    for (int i = 0; i < 4; ++i)
#pragma unroll
        for (int j = 0; j < 4; ++j) acc[i][j] = z4;

    stage(0, 0);
#pragma unroll 2
    for (int kt = 0; kt < 72; ++kt) {
        const int cur = kt & 1;
        __syncthreads();
        if (kt < 71) stage(cur ^ 1, kt + 1);

        const u16* Ab = &As[cur][0];
        const u16* Bb = &Bs[cur][0];
        short8 af[4], bf[4];
#pragma unroll
        for (int i = 0; i < 4; ++i) {
            af[i] = *(const short8*)(Ab + (wm * 64 + i * 16 + lr) * 32 + sw);
            bf[i] = *(const short8*)(Bb + (wn * 64 + i * 16 + lr) * 32 + sw);
        }
#pragma unroll
        for (int i = 0; i < 4; ++i)
#pragma unroll
            for (int j = 0; j < 4; ++j)
                acc[i][j] = __builtin_amdgcn_mfma_f32_16x16x32_bf16(
                    af[i], bf[j], acc[i][j], 0, 0, 0);
    }

    const size_t outn = (size_t)n * 256 * 4096;
#pragma unroll
    for (int i = 0; i < 4; ++i) {
        const int ocb = oc0 + wm * 64 + i * 16 + lq * 4;
#pragma unroll
        for (int j = 0; j < 4; ++j) {
            const int po = pimg + wn * 64 + j * 16 + lr;
            float* op = out + outn + (size_t)ocb * 4096 + po;
#pragma unroll
            for (int r = 0; r < 4; ++r) op[(size_t)r * 4096] = acc[i][j][r];
        }
    }
}

extern "C" void kernel_launch(void* const* d_in, const int* in_sizes, int n_in,
                              void* d_out, int out_size, void* d_ws, size_t ws_size,
                              hipStream_t stream) {
    const float* x  = (const float*)d_in[0];
    const float* z  = (const float*)d_in[1];
    const float* W1 = (const float*)d_in[2];
    const float* B1 = (const float*)d_in[3];
    const float* W2 = (const float*)d_in[4];
    const float* B2 = (const float*)d_in[5];
    float* out = (float*)d_out;

    u16* xp = (u16*)d_ws;
    u16* wb = xp + (size_t)32 * 4356 * 256;
    const size_t need = ((size_t)32 * 4356 * 256 + (size_t)256 * 2304) * 2;
    if (ws_size < need) return;

    nchw2nhwc_pad<<<dim3(8192), dim3(256), 0, stream>>>(x, xp);
    wgen<<<dim3(64), dim3(256), 0, stream>>>(z, W1, B1, W2, B2, wb);
    conv_mfma<<<dim3(2048), dim3(256), 0, stream>>>(xp, wb, out);
}